// Round 5
// baseline (121.456 us; speedup 1.0000x reference)
//
#include <hip/hip_runtime.h>
#include <math.h>

#define BATCH 32
#define HH 512
#define WW 512
#define TH 16                  // output rows per block
#define HALO 2
#define SRH (TH + 2*HALO)      // 20 staged rows
#define NDW (WW / 4)           // 128 dwords per row (u8-packed)
#define CSTRIDE 132            // csum row stride in dwords
#define NPIX ((float)BATCH * HH * WW)
#define HW (HH * WW)
#define NBLK (BATCH * (HH / TH))   // 1024

// ws layout: 8 floats per block (6 used): [bid*8 + j]
// j: 0=ce 1=valid_cnt 2=focal 3=inter 4=sum_bp 5=sum_bt
// Non-atomic: every slot read by finalize is written every call (poison-safe).

__global__ __launch_bounds__(256, 4) void bel_main_kernel(
        const float* __restrict__ pred,
        const int*   __restrict__ target,
        float*       __restrict__ ws) {
    __shared__ unsigned int t8[SRH][NDW];      // target, 1 byte/pixel
    __shared__ unsigned int csum[TH][CSTRIDE]; // vertical 5-sums, packed u8
    __shared__ float red[6][4];

    const int tid = threadIdx.x;
    const int bid = blockIdx.x;
    const int b   = bid >> 5;          // image
    const int ty  = bid & 31;          // row-tile
    const int y0  = ty * TH;
    const size_t tb = (size_t)b * HW;

    // zero the horizontal pad dwords of csum (left=0, right=NDW+1)
    if (tid < 2 * TH) {
        int rr = tid >> 1;
        csum[rr][(tid & 1) ? (NDW + 1) : 0] = 0u;
    }

    // ---- phase A: issue ALL global loads before any LDS dependency ----
    // A1: 10 target int4 loads -> registers (oldest in vmcnt queue)
    int4 Treg[(SRH * NDW) / 256];                      // 10
    #pragma unroll
    for (int it = 0; it < (SRH * NDW) / 256; ++it) {
        const int i  = tid + 256 * it;
        const int r  = i >> 7;
        const int c4 = i & 127;
        const int gy = y0 - HALO + r;
        int4 v = make_int4(0, 0, 0, 0);
        if ((unsigned)gy < (unsigned)HH)
            v = *(const int4*)(target + tb + ((size_t)gy << 9) + (c4 << 2));
        Treg[it] = v;
    }

    // A2: 16 pred float4 loads -> registers (stream behind target loads;
    // staging below only waits for the 10 oldest, so these overlap staging)
    const float4* __restrict__ pr0 = (const float4*)(pred + tb * 2);
    const float4* __restrict__ pr1 = (const float4*)(pred + tb * 2 + HW);
    const int base4 = (y0 << 7) + tid;

    float4 F0[8], F1[8];
    #pragma unroll
    for (int it = 0; it < 8; ++it) F0[it] = pr0[base4 + 256 * it];
    #pragma unroll
    for (int it = 0; it < 8; ++it) F1[it] = pr1[base4 + 256 * it];

    // ---- phase B: pack target to u8 in LDS (waits vmcnt(16) only) ----
    #pragma unroll
    for (int it = 0; it < (SRH * NDW) / 256; ++it) {
        const int i  = tid + 256 * it;
        const int r  = i >> 7;
        const int c4 = i & 127;
        const int4 v = Treg[it];
        t8[r][c4] = (unsigned)v.x | ((unsigned)v.y << 8)
                  | ((unsigned)v.z << 16) | ((unsigned)v.w << 24);
    }
    __syncthreads();

    // ---- vertical 5-sum (packed u8 adds; max byte value 5, no carry) ----
    #pragma unroll
    for (int it = 0; it < (TH * NDW) / 256; ++it) {    // 8 iters
        const int j = tid + 256 * it;
        const int r = j >> 7;
        const int c = j & 127;
        csum[r][c + 1] = t8[r][c] + t8[r+1][c] + t8[r+2][c]
                       + t8[r+3][c] + t8[r+4][c];
    }
    __syncthreads();

    float ce_acc = 0.f, cnt_acc = 0.f, focal_acc = 0.f;
    float inter_acc = 0.f, bp_acc = 0.f, bt_acc = 0.f;

    const unsigned long long M5 = 0xFFFFFFFFFFull;      // 5 bytes
    const unsigned long long ALL5 = 0x0505050505ull;    // box sum == 25

    const int g  = tid & 127;          // loop-invariant column group
    const int rb = tid >> 7;           // 0 or 1

    #pragma unroll
    for (int it = 0; it < 8; ++it) {
        const int r = rb + 2 * it;

        const float4 f0 = F0[it];
        const float4 f1 = F1[it];

        const unsigned int L = csum[r][g];
        const unsigned int M = csum[r][g + 1];
        const unsigned int R = csum[r][g + 2];
        const unsigned int tdw = t8[r + HALO][g];

        const unsigned long long lo  = (unsigned long long)L | ((unsigned long long)M << 32);
        const unsigned long long mid = (unsigned long long)M | ((unsigned long long)R << 32);

        #pragma unroll
        for (int i = 0; i < 4; ++i) {
            unsigned long long w;
            if      (i == 0) w = (lo  >> 16) & M5;
            else if (i == 1) w = (lo  >> 24) & M5;
            else if (i == 2) w =  mid        & M5;
            else             w = (mid >>  8) & M5;
            const float bm = (w != 0ull && w != ALL5) ? 1.0f : 0.0f;

            const unsigned int tv = (tdw >> (8 * i)) & 0xFFu;

            const float p0 = (i == 0) ? f0.x : (i == 1) ? f0.y : (i == 2) ? f0.z : f0.w;
            const float p1 = (i == 0) ? f1.x : (i == 1) ? f1.y : (i == 2) ? f1.z : f1.w;

            const float d  = p1 - p0;
            const float e  = __expf(-fabsf(d));
            const float rz = 1.0f / (1.0f + e);
            const float pmin = e * rz;
            const float prob1 = (d >= 0.0f) ? rz : pmin;
            const float pt = tv ? prob1 : (1.0f - prob1);
            const float ce = -__logf(pt);

            const float valid = (tv != 250u) ? 1.0f : 0.0f;
            ce_acc  += ce * valid;
            cnt_acc += valid;

            const float omp = 1.0f - pt;
            focal_acc += omp * omp * ce;                // *0.25 folded at the end

            const float bp = prob1 * bm;
            const float bt = (float)tv * bm;
            inter_acc += bp * bt;
            bp_acc    += bp;
            bt_acc    += bt;
        }
    }

    // ---- block reduction ----
    float vals[6] = {ce_acc, cnt_acc, focal_acc * 0.25f, inter_acc, bp_acc, bt_acc};
    #pragma unroll
    for (int jj = 0; jj < 6; ++jj) {
        float v = vals[jj];
        #pragma unroll
        for (int off = 32; off > 0; off >>= 1)
            v += __shfl_down(v, off, 64);
        vals[jj] = v;
    }
    const int wave = tid >> 6;
    const int lane = tid & 63;
    if (lane == 0) {
        #pragma unroll
        for (int jj = 0; jj < 6; ++jj) red[jj][wave] = vals[jj];
    }
    __syncthreads();
    if (tid == 0) {
        float* p = ws + bid * 8;
        #pragma unroll
        for (int jj = 0; jj < 6; ++jj)
            p[jj] = red[jj][0] + red[jj][1] + red[jj][2] + red[jj][3];
    }
}

__global__ void bel_finalize_kernel(const float* __restrict__ ws,
                                    float* __restrict__ out) {
    __shared__ float simg[BATCH][4];
    const int t = threadIdx.x;          // 256 threads
    const int b = t >> 3;               // image 0..31
    const int s = t & 7;                // 8 lanes per image

    float a0 = 0.f, a1 = 0.f, a2 = 0.f, a3 = 0.f, a4 = 0.f, a5 = 0.f;
    #pragma unroll
    for (int k = 0; k < 4; ++k) {
        const int bid = (b << 5) + s + (k << 3);
        const float* p = ws + bid * 8;
        a0 += p[0]; a1 += p[1]; a2 += p[2];
        a3 += p[3]; a4 += p[4]; a5 += p[5];
    }
    #pragma unroll
    for (int off = 4; off > 0; off >>= 1) {
        a0 += __shfl_down(a0, off, 8);
        a1 += __shfl_down(a1, off, 8);
        a2 += __shfl_down(a2, off, 8);
        a3 += __shfl_down(a3, off, 8);
        a4 += __shfl_down(a4, off, 8);
        a5 += __shfl_down(a5, off, 8);
    }
    if (s == 0) {
        simg[b][0] = a0;
        simg[b][1] = a1;
        simg[b][2] = a2;
        simg[b][3] = 2.0f * a3 / (a4 + a5 + 1e-8f);   // dice_b
    }
    __syncthreads();
    if (t < BATCH) {
        float ce  = simg[t][0];
        float cnt = simg[t][1];
        float foc = simg[t][2];
        float dc  = simg[t][3];
        #pragma unroll
        for (int off = 16; off > 0; off >>= 1) {
            ce  += __shfl_down(ce,  off, 32);
            cnt += __shfl_down(cnt, off, 32);
            foc += __shfl_down(foc, off, 32);
            dc  += __shfl_down(dc,  off, 32);
        }
        if (t == 0) {
            const float ce_loss = ce / fmaxf(cnt, 1.0f);
            const float focal   = foc / NPIX;
            const float bdice   = 1.0f - dc / (float)BATCH;
            out[0] = ce_loss + focal + bdice;   // BOUNDARY_W = 1.0
        }
    }
}

extern "C" void kernel_launch(void* const* d_in, const int* in_sizes, int n_in,
                              void* d_out, int out_size, void* d_ws, size_t ws_size,
                              hipStream_t stream) {
    const float* pred   = (const float*)d_in[0];
    const int*   target = (const int*)d_in[1];
    float* ws  = (float*)d_ws;
    float* out = (float*)d_out;

    bel_main_kernel<<<NBLK, 256, 0, stream>>>(pred, target, ws);
    bel_finalize_kernel<<<1, 256, 0, stream>>>(ws, out);
}

// Round 6
// 120.896 us; speedup vs baseline: 1.0046x; 1.0046x over previous
//
#include <hip/hip_runtime.h>
#include <math.h>

#define BATCH 32
#define HH 512
#define WW 512
#define TH 8                   // output rows per block
#define HALO 2
#define SRH (TH + 2*HALO)      // 12 staged rows
#define NDW (WW / 4)           // 128 dwords per row (u8-packed)
#define CSTRIDE 132            // csum row stride in dwords
#define NPIX ((float)BATCH * HH * WW)
#define HW (HH * WW)
#define TILES (HH / TH)            // 64 tiles per image
#define NBLK (BATCH * TILES)       // 2048

#define NSTG ((SRH * NDW) / 256)   // 6 staging iters/thread
#define NCS  ((TH * NDW) / 256)    // 4 csum iters/thread
#define NCMP ((TH * NDW) / 256)    // 4 compute iters/thread (4 px each)

// ws layout: 8 floats per block (6 used): [bid*8 + j]
// j: 0=ce 1=valid_cnt 2=focal 3=inter 4=sum_bp 5=sum_bt
// Non-atomic: every slot read by finalize is written every call (poison-safe).

__global__ __launch_bounds__(256) void bel_main_kernel(
        const float* __restrict__ pred,
        const int*   __restrict__ target,
        float*       __restrict__ ws) {
    __shared__ unsigned int t8[SRH][NDW];      // target, 1 byte/pixel
    __shared__ unsigned int csum[TH][CSTRIDE]; // vertical 5-sums, packed u8
    __shared__ float red[6][4];

    const int tid = threadIdx.x;
    const int bid = blockIdx.x;
    const int b   = bid >> 6;          // image
    const int ty  = bid & 63;          // row-tile
    const int y0  = ty * TH;
    const size_t tb = (size_t)b * HW;

    // zero the horizontal pad dwords of csum (left=0, right=NDW+1)
    if (tid < 2 * TH) {
        int rr = tid >> 1;
        csum[rr][(tid & 1) ? (NDW + 1) : 0] = 0u;
    }

    // ---- phase A: issue ALL global loads up front ----
    // A1: target int4 loads (oldest in the vmcnt queue)
    int4 Treg[NSTG];
    #pragma unroll
    for (int it = 0; it < NSTG; ++it) {
        const int i  = tid + 256 * it;
        const int r  = i >> 7;
        const int c4 = i & 127;
        const int gy = y0 - HALO + r;
        int4 v = make_int4(0, 0, 0, 0);
        if ((unsigned)gy < (unsigned)HH)
            v = *(const int4*)(target + tb + ((size_t)gy << 9) + (c4 << 2));
        Treg[it] = v;
    }

    // A2: all pred float4 loads (younger; staging waits only for targets)
    const float4* __restrict__ pr0 = (const float4*)(pred + tb * 2);
    const float4* __restrict__ pr1 = (const float4*)(pred + tb * 2 + HW);
    const int base4 = (y0 << 7) + tid;

    float4 F0[NCMP], F1[NCMP];
    #pragma unroll
    for (int it = 0; it < NCMP; ++it) F0[it] = pr0[base4 + 256 * it];
    #pragma unroll
    for (int it = 0; it < NCMP; ++it) F1[it] = pr1[base4 + 256 * it];

    // Pin the schedule: nothing may cross — keeps pred loads issued HERE,
    // before the pack below forces its (target-only) vmcnt wait.
    __builtin_amdgcn_sched_barrier(0);

    // ---- phase B: pack target to u8 in LDS (waits vmcnt(NCMP*2) only) ----
    #pragma unroll
    for (int it = 0; it < NSTG; ++it) {
        const int i  = tid + 256 * it;
        const int r  = i >> 7;
        const int c4 = i & 127;
        const int4 v = Treg[it];
        t8[r][c4] = (unsigned)v.x | ((unsigned)v.y << 8)
                  | ((unsigned)v.z << 16) | ((unsigned)v.w << 24);
    }
    __syncthreads();

    // ---- vertical 5-sum (packed u8 adds; max byte value 5, no carry) ----
    #pragma unroll
    for (int it = 0; it < NCS; ++it) {
        const int j = tid + 256 * it;
        const int r = j >> 7;
        const int c = j & 127;
        csum[r][c + 1] = t8[r][c] + t8[r+1][c] + t8[r+2][c]
                       + t8[r+3][c] + t8[r+4][c];
    }
    __syncthreads();

    float ce_acc = 0.f, cnt_acc = 0.f, focal_acc = 0.f;
    float inter_acc = 0.f, bp_acc = 0.f, bt_acc = 0.f;

    const unsigned long long M5 = 0xFFFFFFFFFFull;      // 5 bytes
    const unsigned long long ALL5 = 0x0505050505ull;    // box sum == 25

    const int g  = tid & 127;          // loop-invariant column group
    const int rb = tid >> 7;           // 0 or 1

    #pragma unroll
    for (int it = 0; it < NCMP; ++it) {
        const int r = rb + 2 * it;

        const float4 f0 = F0[it];
        const float4 f1 = F1[it];

        const unsigned int L = csum[r][g];
        const unsigned int M = csum[r][g + 1];
        const unsigned int R = csum[r][g + 2];
        const unsigned int tdw = t8[r + HALO][g];

        const unsigned long long lo  = (unsigned long long)L | ((unsigned long long)M << 32);
        const unsigned long long mid = (unsigned long long)M | ((unsigned long long)R << 32);

        #pragma unroll
        for (int i = 0; i < 4; ++i) {
            unsigned long long w;
            if      (i == 0) w = (lo  >> 16) & M5;
            else if (i == 1) w = (lo  >> 24) & M5;
            else if (i == 2) w =  mid        & M5;
            else             w = (mid >>  8) & M5;
            const float bm = (w != 0ull && w != ALL5) ? 1.0f : 0.0f;

            const unsigned int tv = (tdw >> (8 * i)) & 0xFFu;

            const float p0 = (i == 0) ? f0.x : (i == 1) ? f0.y : (i == 2) ? f0.z : f0.w;
            const float p1 = (i == 0) ? f1.x : (i == 1) ? f1.y : (i == 2) ? f1.z : f1.w;

            const float d  = p1 - p0;
            const float e  = __expf(-fabsf(d));
            const float rz = 1.0f / (1.0f + e);
            const float pmin = e * rz;
            const float prob1 = (d >= 0.0f) ? rz : pmin;
            const float pt = tv ? prob1 : (1.0f - prob1);
            const float ce = -__logf(pt);

            const float valid = (tv != 250u) ? 1.0f : 0.0f;
            ce_acc  += ce * valid;
            cnt_acc += valid;

            const float omp = 1.0f - pt;
            focal_acc += omp * omp * ce;                // *0.25 folded at the end

            const float bp = prob1 * bm;
            const float bt = (float)tv * bm;
            inter_acc += bp * bt;
            bp_acc    += bp;
            bt_acc    += bt;
        }
    }

    // ---- block reduction ----
    float vals[6] = {ce_acc, cnt_acc, focal_acc * 0.25f, inter_acc, bp_acc, bt_acc};
    #pragma unroll
    for (int jj = 0; jj < 6; ++jj) {
        float v = vals[jj];
        #pragma unroll
        for (int off = 32; off > 0; off >>= 1)
            v += __shfl_down(v, off, 64);
        vals[jj] = v;
    }
    const int wave = tid >> 6;
    const int lane = tid & 63;
    if (lane == 0) {
        #pragma unroll
        for (int jj = 0; jj < 6; ++jj) red[jj][wave] = vals[jj];
    }
    __syncthreads();
    if (tid == 0) {
        float* p = ws + bid * 8;
        #pragma unroll
        for (int jj = 0; jj < 6; ++jj)
            p[jj] = red[jj][0] + red[jj][1] + red[jj][2] + red[jj][3];
    }
}

__global__ void bel_finalize_kernel(const float* __restrict__ ws,
                                    float* __restrict__ out) {
    __shared__ float simg[BATCH][4];
    const int t = threadIdx.x;          // 256 threads
    const int b = t >> 3;               // image 0..31
    const int s = t & 7;                // 8 lanes per image

    float a0 = 0.f, a1 = 0.f, a2 = 0.f, a3 = 0.f, a4 = 0.f, a5 = 0.f;
    #pragma unroll
    for (int k = 0; k < TILES / 8; ++k) {   // 8 tiles per lane
        const int bid = (b << 6) + s + (k << 3);
        const float* p = ws + bid * 8;
        a0 += p[0]; a1 += p[1]; a2 += p[2];
        a3 += p[3]; a4 += p[4]; a5 += p[5];
    }
    #pragma unroll
    for (int off = 4; off > 0; off >>= 1) {
        a0 += __shfl_down(a0, off, 8);
        a1 += __shfl_down(a1, off, 8);
        a2 += __shfl_down(a2, off, 8);
        a3 += __shfl_down(a3, off, 8);
        a4 += __shfl_down(a4, off, 8);
        a5 += __shfl_down(a5, off, 8);
    }
    if (s == 0) {
        simg[b][0] = a0;
        simg[b][1] = a1;
        simg[b][2] = a2;
        simg[b][3] = 2.0f * a3 / (a4 + a5 + 1e-8f);   // dice_b
    }
    __syncthreads();
    if (t < BATCH) {
        float ce  = simg[t][0];
        float cnt = simg[t][1];
        float foc = simg[t][2];
        float dc  = simg[t][3];
        #pragma unroll
        for (int off = 16; off > 0; off >>= 1) {
            ce  += __shfl_down(ce,  off, 32);
            cnt += __shfl_down(cnt, off, 32);
            foc += __shfl_down(foc, off, 32);
            dc  += __shfl_down(dc,  off, 32);
        }
        if (t == 0) {
            const float ce_loss = ce / fmaxf(cnt, 1.0f);
            const float focal   = foc / NPIX;
            const float bdice   = 1.0f - dc / (float)BATCH;
            out[0] = ce_loss + focal + bdice;   // BOUNDARY_W = 1.0
        }
    }
}

extern "C" void kernel_launch(void* const* d_in, const int* in_sizes, int n_in,
                              void* d_out, int out_size, void* d_ws, size_t ws_size,
                              hipStream_t stream) {
    const float* pred   = (const float*)d_in[0];
    const int*   target = (const int*)d_in[1];
    float* ws  = (float*)d_ws;
    float* out = (float*)d_out;

    bel_main_kernel<<<NBLK, 256, 0, stream>>>(pred, target, ws);
    bel_finalize_kernel<<<1, 256, 0, stream>>>(ws, out);
}